// Round 9
// baseline (381.941 us; speedup 1.0000x reference)
//
#include <hip/hip_runtime.h>
#include <hip/hip_bf16.h>
#include <math.h>

#define NN 50000
#define EE 800000
#define GG 256

typedef short bf16x8 __attribute__((ext_vector_type(8)));
typedef float f32x4 __attribute__((ext_vector_type(4)));
typedef unsigned int u32x4 __attribute__((ext_vector_type(4)));

__device__ __forceinline__ unsigned short f2bf(float x) {
    __hip_bfloat16 h = __float2bfloat16(x);
    union { __hip_bfloat16 h; unsigned short u; } c; c.h = h; return c.u;
}
__device__ __forceinline__ float bf2f(unsigned short u) {
    union { unsigned int v; float f; } t; t.v = ((unsigned int)u) << 16; return t.f;
}
__device__ __forceinline__ float gelu_f(float v) {
    return 0.5f * v * (1.0f + erff(v * 0.70710678118654752f));
}
// XOR swizzle for [rows][128 bf16] LDS tiles (256B row stride)
__device__ __forceinline__ int swz(int row, int bytecol) {
    return row * 256 + (bytecol ^ ((row & 7) << 4));
}

// ---------------- graph prep ----------------
__global__ void k_deg(const int* __restrict__ dst, int* __restrict__ degi, int E) {
    int i = blockIdx.x * blockDim.x + threadIdx.x;
    if (i < E) atomicAdd(&degi[dst[i]], 1);
}
__global__ void k_scan1(const int* __restrict__ degi, int* __restrict__ incl,
                        int* __restrict__ bsum, int N) {
    __shared__ int sm[1024];
    int t = threadIdx.x, i = blockIdx.x * 1024 + t;
    int v = (i < N) ? degi[i] : 0;
    sm[t] = v;
    __syncthreads();
    for (int off = 1; off < 1024; off <<= 1) {
        int add = (t >= off) ? sm[t - off] : 0;
        __syncthreads();
        sm[t] += add;
        __syncthreads();
    }
    if (i < N) incl[i] = sm[t];
    if (t == 1023) bsum[blockIdx.x] = sm[t];
}
// rowstart = exclusive scan (block offset via wave-reduce over bsum) ; + dis
__global__ void k_scan3(const int* __restrict__ incl, const int* __restrict__ degi,
                        const int* __restrict__ bsum, float* __restrict__ dis,
                        int* __restrict__ rowstart, int N, int E, int nsb) {
    __shared__ int sboff;
    int t = threadIdx.x;
    if (t < 64) {
        int nb = blockIdx.x >> 2;
        int v = (t < nb && t < nsb) ? bsum[t] : 0;
        #pragma unroll
        for (int o = 1; o < 64; o <<= 1) v += __shfl_xor(v, o, 64);
        if (t == 0) sboff = v;
    }
    __syncthreads();
    int i = blockIdx.x * 256 + t;
    if (i < N) {
        rowstart[i] = incl[i] - degi[i] + sboff;
        dis[i] = rsqrtf((float)(degi[i] + 1)); // +1 self loop
    }
    if (i == 0) rowstart[N] = E;
}
__global__ void k_fill(const int* __restrict__ src, const int* __restrict__ dst,
                       const int* __restrict__ rowstart,
                       int* __restrict__ fillc, int* __restrict__ col, int E) {
    int i = blockIdx.x * blockDim.x + threadIdx.x;
    if (i < E) {
        int s = src[i], d = dst[i];
        int pos = rowstart[d] + atomicAdd(&fillc[d], 1);
        col[pos] = s;
    }
}
// all 8 weight matrices fp32 [k][n] -> bf16 transposed+preswizzled, one launch
__global__ void k_prepw8(const float* __restrict__ w0, const float* __restrict__ w1,
                         const float* __restrict__ w2, const float* __restrict__ w3,
                         const float* __restrict__ w4, const float* __restrict__ w5,
                         const float* __restrict__ w6, const float* __restrict__ w7,
                         unsigned short* __restrict__ Wt) {
    int b = blockIdx.x >> 6;
    const float* W = b == 0 ? w0 : b == 1 ? w1 : b == 2 ? w2 : b == 3 ? w3
                   : b == 4 ? w4 : b == 5 ? w5 : b == 6 ? w6 : w7;
    int tid = (blockIdx.x & 63) * 256 + threadIdx.x;
    int n = tid >> 7, k = tid & 127;
    *(unsigned short*)((char*)(Wt + (size_t)b * 16384) + swz(n, k * 2)) = f2bf(W[k * 128 + n]);
}

// ---------------- fused 3-matmul chain ----------------
// x' = [BN](A); h = gelu(x'@W1+b1); y = h@W2+b2 [+ x' residual] -> outx32 /
// fused graph-pool; optional stage3: out3 = bf16(dis[row] * (y@W3)).
__global__ __launch_bounds__(256) void k_mm(
    const float* __restrict__ A32, const unsigned short* __restrict__ A16,
    const unsigned short* __restrict__ W1, const float* __restrict__ b1,
    const unsigned short* __restrict__ W2, const float* __restrict__ b2,
    const unsigned short* __restrict__ W3, const float* __restrict__ disv,
    const float* __restrict__ st_sum, const float* __restrict__ st_sq,
    const float* __restrict__ st_g, const float* __restrict__ st_b,
    float invN, int bn, int hasres,
    float* __restrict__ outx32, unsigned short* __restrict__ out3,
    const int* __restrict__ batch, float* __restrict__ pooled, int M)
{
    __shared__ unsigned short As[64 * 128];
    __shared__ unsigned short Ws[128 * 128];
    __shared__ float lsc[128], lsh[128];
    __shared__ float sdis[64];
    __shared__ int gid[64];
    const int tid = threadIdx.x;
    const int bm = blockIdx.x * 64;
    if (st_sum && tid < 128) {
        float m = st_sum[tid] * invN;
        float var = st_sq[tid] * invN - m * m;
        float s = st_g[tid] * rsqrtf(var + 1e-5f);
        lsc[tid] = s;
        lsh[tid] = st_b[tid] - m * s;
    }
    __syncthreads();
    { // stage W1
        const uint4* srcp = (const uint4*)W1;
        uint4* dstp = (uint4*)Ws;
        for (int i = tid; i < 2048; i += 256) dstp[i] = srcp[i];
    }
    // stage A, 4 passes of 16 rows; optional BN affine
    #pragma unroll
    for (int pass = 0; pass < 4; ++pass) {
        int row = pass * 16 + (tid >> 4);
        int c8 = tid & 15;
        int gr = bm + row; if (gr > M - 1) gr = M - 1;
        float vv[8];
        if (A32) {
            const float* pp = A32 + (size_t)gr * 128 + c8 * 8;
            float4 v0 = *(const float4*)pp;
            float4 v1 = *(const float4*)(pp + 4);
            vv[0] = v0.x; vv[1] = v0.y; vv[2] = v0.z; vv[3] = v0.w;
            vv[4] = v1.x; vv[5] = v1.y; vv[6] = v1.z; vv[7] = v1.w;
        } else {
            u32x4 raw = __builtin_nontemporal_load((const u32x4*)(A16 + (size_t)gr * 128 + c8 * 8));
            #pragma unroll
            for (int d = 0; d < 4; ++d) {
                vv[2 * d]     = bf2f((unsigned short)(raw[d] & 0xffff));
                vv[2 * d + 1] = bf2f((unsigned short)(raw[d] >> 16));
            }
        }
        if (bn) {
            int ch = c8 * 8;
            #pragma unroll
            for (int j = 0; j < 8; ++j) vv[j] = vv[j] * lsc[ch + j] + lsh[ch + j];
        }
        unsigned short tmp[8];
        #pragma unroll
        for (int j = 0; j < 8; ++j) tmp[j] = f2bf(vv[j]);
        *(uint4*)((char*)As + swz(row, c8 * 16)) = *(uint4*)tmp;
    }
    __syncthreads();

    const int lane = tid & 63, wid = tid >> 6;
    const int r0 = wid * 16;
    const int lrow = lane & 15;
    const int lkb = (lane >> 4) * 16;
    const int cb = lane & 15;
    const int rb = r0 + (lane >> 4) * 4;

    f32x4 acc[8];
    // ---- mm1 ----
    #pragma unroll
    for (int n = 0; n < 8; ++n) acc[n] = (f32x4){0.f, 0.f, 0.f, 0.f};
    #pragma unroll
    for (int kk = 0; kk < 4; ++kk) {
        int bc = kk * 64 + lkb;
        bf16x8 a = *(const bf16x8*)((const char*)As + swz(r0 + lrow, bc));
        #pragma unroll
        for (int n = 0; n < 8; ++n) {
            bf16x8 b = *(const bf16x8*)((const char*)Ws + swz(n * 16 + lrow, bc));
            acc[n] = __builtin_amdgcn_mfma_f32_16x16x32_bf16(a, b, acc[n], 0, 0, 0);
        }
    }
    // capture residual x' (BN'd A) from own epilogue slots BEFORE epi1 overwrites
    unsigned short rres[32];
    if (hasres) {
        #pragma unroll
        for (int n = 0; n < 8; ++n)
            #pragma unroll
            for (int j = 0; j < 4; ++j)
                rres[n * 4 + j] = *(const unsigned short*)((const char*)As + swz(rb + j, (n * 16 + cb) * 2));
    }
    // epi1: gelu -> h into own As slab (rows rb..rb+3 are wave-private)
    #pragma unroll
    for (int n = 0; n < 8; ++n) {
        int colg = n * 16 + cb;
        float bv = b1[colg];
        #pragma unroll
        for (int j = 0; j < 4; ++j) {
            float v = gelu_f(acc[n][j] + bv);
            *(unsigned short*)((char*)As + swz(rb + j, colg * 2)) = f2bf(v);
        }
    }
    __syncthreads(); // all waves done reading W1
    { // stage W2
        const uint4* srcp = (const uint4*)W2;
        uint4* dstp = (uint4*)Ws;
        for (int i = tid; i < 2048; i += 256) dstp[i] = srcp[i];
    }
    __syncthreads();
    // ---- mm2 ----
    #pragma unroll
    for (int n = 0; n < 8; ++n) acc[n] = (f32x4){0.f, 0.f, 0.f, 0.f};
    #pragma unroll
    for (int kk = 0; kk < 4; ++kk) {
        int bc = kk * 64 + lkb;
        bf16x8 a = *(const bf16x8*)((const char*)As + swz(r0 + lrow, bc));
        #pragma unroll
        for (int n = 0; n < 8; ++n) {
            bf16x8 b = *(const bf16x8*)((const char*)Ws + swz(n * 16 + lrow, bc));
            acc[n] = __builtin_amdgcn_mfma_f32_16x16x32_bf16(a, b, acc[n], 0, 0, 0);
        }
    }
    const int dopool = (pooled != nullptr);
    float* wsf = (float*)Ws; // free when !W3 (pool-only in final chain)
    // epi2: + b2 (+ register residual) -> outx32 / pool staging; bf16 into As for stage3
    #pragma unroll
    for (int n = 0; n < 8; ++n) {
        int colg = n * 16 + cb;
        float bv = b2[colg];
        #pragma unroll
        for (int j = 0; j < 4; ++j) {
            int rowg = bm + rb + j;
            float v = acc[n][j] + bv;
            if (hasres) v += bf2f(rres[n * 4 + j]);
            if (outx32 && rowg < M) outx32[(size_t)rowg * 128 + colg] = v;
            if (W3) *(unsigned short*)((char*)As + swz(rb + j, colg * 2)) = f2bf(v);
            if (dopool) wsf[(rb + j) * 128 + colg] = v;
        }
    }
    if (dopool) {
        if (tid < 64) { int r = bm + tid; gid[tid] = (r < M) ? batch[r] : -1; }
        __syncthreads();
        if (tid < 128) {
            float pacc = 0.f;
            int gcur = gid[0];
            #pragma unroll 4
            for (int r = 0; r < 64; ++r) {
                int gg = gid[r];
                if (gg != gcur) {
                    if (gcur >= 0) atomicAdd(&pooled[(size_t)gcur * 128 + tid], pacc);
                    pacc = 0.f; gcur = gg;
                }
                if (gg >= 0) pacc += wsf[r * 128 + tid];
            }
            if (gcur >= 0) atomicAdd(&pooled[(size_t)gcur * 128 + tid], pacc);
        }
        return;
    }
    if (!W3) return;
    __syncthreads(); // all waves done reading W2
    { // stage W3 + dis slice
        const uint4* srcp = (const uint4*)W3;
        uint4* dstp = (uint4*)Ws;
        for (int i = tid; i < 2048; i += 256) dstp[i] = srcp[i];
        if (tid < 64) { int r = bm + tid; sdis[tid] = disv[(r < M) ? r : (M - 1)]; }
    }
    __syncthreads();
    // ---- mm3 (conv, pre-scaled by dis[row]) ----
    #pragma unroll
    for (int n = 0; n < 8; ++n) acc[n] = (f32x4){0.f, 0.f, 0.f, 0.f};
    #pragma unroll
    for (int kk = 0; kk < 4; ++kk) {
        int bc = kk * 64 + lkb;
        bf16x8 a = *(const bf16x8*)((const char*)As + swz(r0 + lrow, bc));
        #pragma unroll
        for (int n = 0; n < 8; ++n) {
            bf16x8 b = *(const bf16x8*)((const char*)Ws + swz(n * 16 + lrow, bc));
            acc[n] = __builtin_amdgcn_mfma_f32_16x16x32_bf16(a, b, acc[n], 0, 0, 0);
        }
    }
    #pragma unroll
    for (int n = 0; n < 8; ++n) {
        int colg = n * 16 + cb;
        #pragma unroll
        for (int j = 0; j < 4; ++j) {
            int rowg = bm + rb + j;
            if (rowg < M) out3[(size_t)rowg * 128 + colg] = f2bf(acc[n][j] * sdis[rb + j]);
        }
    }
}

// ---------------- CSR aggregation (unweighted sum of dis-prescaled rows) ----------------
// z_v = dis_v * (sum_u xws_u + xws_v) + conv_b + x_v ; BN partial stats.
__global__ __launch_bounds__(256) void k_agg(
    const unsigned short* __restrict__ xws, const int* __restrict__ rowstart,
    const int* __restrict__ col,
    const float* __restrict__ dis, const float* __restrict__ convb,
    const float* __restrict__ x0, unsigned short* __restrict__ zbf,
    float* __restrict__ bnsum, float* __restrict__ bnsq, int N)
{
    __shared__ float redS[4][128];
    __shared__ float redQ[4][128];
    const int tid = threadIdx.x;
    const int lane = tid & 63;
    const int wid = tid >> 6;
    const int g = lane >> 4;
    const int cl = lane & 15;
    const int ch = cl * 8;
    const int wave = blockIdx.x * 4 + wid;
    const int nwaves = gridDim.x * 4;

    float cb[8];
    #pragma unroll
    for (int j = 0; j < 8; ++j) cb[j] = convb[ch + j];
    float s[8], q[8];
    #pragma unroll
    for (int j = 0; j < 8; ++j) { s[j] = 0.f; q[j] = 0.f; }

    for (int v = wave; v < N; v += nwaves) {
        const int e0 = rowstart[v], e1 = rowstart[v + 1];
        float a[8];
        #pragma unroll
        for (int j = 0; j < 8; ++j) a[j] = 0.f;
        int e = e0 + g;
        // 4-wide: 4 independent gathers in flight per iteration (16 edges/wave)
        for (; e + 12 < e1; e += 16) {
            const int u0 = col[e];
            const int u1 = col[e + 4];
            const int u2 = col[e + 8];
            const int u3 = col[e + 12];
            u32x4 p0 = *(const u32x4*)(xws + (size_t)u0 * 128 + ch);
            u32x4 p1 = *(const u32x4*)(xws + (size_t)u1 * 128 + ch);
            u32x4 p2 = *(const u32x4*)(xws + (size_t)u2 * 128 + ch);
            u32x4 p3 = *(const u32x4*)(xws + (size_t)u3 * 128 + ch);
            #pragma unroll
            for (int d = 0; d < 4; ++d) {
                a[2 * d]     += bf2f((unsigned short)(p0[d] & 0xffff)) + bf2f((unsigned short)(p1[d] & 0xffff))
                              + bf2f((unsigned short)(p2[d] & 0xffff)) + bf2f((unsigned short)(p3[d] & 0xffff));
                a[2 * d + 1] += bf2f((unsigned short)(p0[d] >> 16)) + bf2f((unsigned short)(p1[d] >> 16))
                              + bf2f((unsigned short)(p2[d] >> 16)) + bf2f((unsigned short)(p3[d] >> 16));
            }
        }
        for (; e + 4 < e1; e += 8) {
            const int u0 = col[e];
            const int u1 = col[e + 4];
            u32x4 p0 = *(const u32x4*)(xws + (size_t)u0 * 128 + ch);
            u32x4 p1 = *(const u32x4*)(xws + (size_t)u1 * 128 + ch);
            #pragma unroll
            for (int d = 0; d < 4; ++d) {
                a[2 * d]     += bf2f((unsigned short)(p0[d] & 0xffff)) + bf2f((unsigned short)(p1[d] & 0xffff));
                a[2 * d + 1] += bf2f((unsigned short)(p0[d] >> 16)) + bf2f((unsigned short)(p1[d] >> 16));
            }
        }
        if (e < e1) {
            const int u = col[e];
            u32x4 p = *(const u32x4*)(xws + (size_t)u * 128 + ch);
            #pragma unroll
            for (int d = 0; d < 4; ++d) {
                a[2 * d]     += bf2f((unsigned short)(p[d] & 0xffff));
                a[2 * d + 1] += bf2f((unsigned short)(p[d] >> 16));
            }
        }
        #pragma unroll
        for (int j = 0; j < 8; ++j) {
            a[j] += __shfl_xor(a[j], 16, 64);
            a[j] += __shfl_xor(a[j], 32, 64);
        }
        if (g == 0) {
            const float dv = dis[v];
            u32x4 p = *(const u32x4*)(xws + (size_t)v * 128 + ch); // self (pre-scaled)
            f32x4 xa = __builtin_nontemporal_load((const f32x4*)(x0 + (size_t)v * 128 + ch));
            f32x4 xb = __builtin_nontemporal_load((const f32x4*)(x0 + (size_t)v * 128 + ch + 4));
            const float xr[8] = { xa[0], xa[1], xa[2], xa[3], xb[0], xb[1], xb[2], xb[3] };
            float zz[8];
            #pragma unroll
            for (int d = 0; d < 4; ++d) {
                zz[2 * d]     = dv * (a[2 * d]     + bf2f((unsigned short)(p[d] & 0xffff)));
                zz[2 * d + 1] = dv * (a[2 * d + 1] + bf2f((unsigned short)(p[d] >> 16)));
            }
            unsigned short zo[8];
            #pragma unroll
            for (int j = 0; j < 8; ++j) {
                zz[j] += cb[j] + xr[j];
                s[j] += zz[j];
                q[j] += zz[j] * zz[j];
                zo[j] = f2bf(zz[j]);
            }
            __builtin_nontemporal_store(*(const u32x4*)zo, (u32x4*)(zbf + (size_t)v * 128 + ch));
        }
    }
    if (g == 0) {
        #pragma unroll
        for (int j = 0; j < 8; ++j) { redS[wid][ch + j] = s[j]; redQ[wid][ch + j] = q[j]; }
    }
    __syncthreads();
    if (tid < 128) {
        float ts = redS[0][tid] + redS[1][tid] + redS[2][tid] + redS[3][tid];
        float tq = redQ[0][tid] + redQ[1][tid] + redQ[2][tid] + redQ[3][tid];
        atomicAdd(&bnsum[tid], ts);
        atomicAdd(&bnsq[tid], tq);
    }
}
// post FFNN (exact fp32); per-graph counts via binary search over sorted batch
__global__ __launch_bounds__(128) void k_post(
    const float* __restrict__ pooled, const int* __restrict__ batch,
    const float* __restrict__ w1, const float* __restrict__ b1,
    const float* __restrict__ w2, const float* __restrict__ b2,
    float* __restrict__ out, int N, int G)
{
    __shared__ float pr[128], hr[128];
    __shared__ int bounds[2];
    int g = blockIdx.x, t = threadIdx.x;
    if (t < 2) {
        int tgt = g + t, lo = 0, hi = N;
        while (lo < hi) { int mid = (lo + hi) >> 1; if (batch[mid] < tgt) lo = mid + 1; else hi = mid; }
        bounds[t] = lo;
    }
    __syncthreads();
    float c = fmaxf((float)(bounds[1] - bounds[0]), 1.0f);
    pr[t] = pooled[(size_t)g * 128 + t] / c;
    __syncthreads();
    float a = b1[t];
    for (int k = 0; k < 128; ++k) a += pr[k] * w1[k * 128 + t];
    hr[t] = gelu_f(a);
    __syncthreads();
    if (t < 64) {
        float o = b2[t];
        for (int k = 0; k < 128; ++k) o += hr[k] * w2[k * 64 + t];
        out[g * 64 + t] = o;
    }
}

extern "C" void kernel_launch(void* const* d_in, const int* in_sizes, int n_in,
                              void* d_out, int out_size, void* d_ws, size_t ws_size,
                              hipStream_t stream) {
    (void)in_sizes; (void)n_in; (void)out_size; (void)ws_size;
    const float* x_in    = (const float*)d_in[0];
    const int*   ei      = (const int*)d_in[1];
    const int*   batch   = (const int*)d_in[2];
    const float* pre_w1  = (const float*)d_in[3];
    const float* pre_b1  = (const float*)d_in[4];
    const float* pre_w2  = (const float*)d_in[5];
    const float* pre_b2  = (const float*)d_in[6];
    const float* conv_w  = (const float*)d_in[7];
    const float* conv_b  = (const float*)d_in[8];
    const float* ffnn_w1 = (const float*)d_in[9];
    const float* ffnn_b1 = (const float*)d_in[10];
    const float* ffnn_w2 = (const float*)d_in[11];
    const float* ffnn_b2 = (const float*)d_in[12];
    const float* bn_gamma= (const float*)d_in[13];
    const float* bn_beta = (const float*)d_in[14];
    const float* post_w1 = (const float*)d_in[15];
    const float* post_b1 = (const float*)d_in[16];
    const float* post_w2 = (const float*)d_in[17];
    const float* post_b2 = (const float*)d_in[18];
    const int* srcE = ei;
    const int* dstE = ei + EE;

    char* base = (char*)d_ws;
    size_t off = 0;
    auto carve = [&](size_t bytes) {
        char* q = base + off;
        off = (off + bytes + 255) & ~(size_t)255;
        return q;
    };
    float* xf32 = (float*)carve((size_t)NN * 128 * 4);
    unsigned short* zbf = (unsigned short*)carve((size_t)NN * 128 * 2);
    unsigned short* hbf = (unsigned short*)carve((size_t)NN * 128 * 2); // xws scratch
    float* dis   = (float*)carve((size_t)NN * 4);
    // zero-region: degi, fillc, pooled, bnstat contiguous -> ONE memset
    int*   degi  = (int*)carve((size_t)NN * 4);
    int*   fillc = (int*)carve((size_t)NN * 4);
    float* pooled= (float*)carve((size_t)GG * 128 * 4);
    float* bnstat= (float*)carve(512 * 4); // [hop][sum|sq][128]
    size_t zlen  = (size_t)((char*)(bnstat + 512) - (char*)degi);
    int* incl    = (int*)carve((size_t)NN * 4);
    int* bsum    = (int*)carve(64 * 4);
    int* rowstart= (int*)carve((size_t)(NN + 1) * 4);
    int* colx    = (int*)carve((size_t)EE * 4);
    unsigned short* Wt = (unsigned short*)carve((size_t)8 * 16384 * 2);

    hipMemsetAsync(degi, 0, zlen, stream);

    const int nsb = (NN + 1023) / 1024;
    k_deg<<<(EE + 255) / 256, 256, 0, stream>>>(dstE, degi, EE);
    k_scan1<<<nsb, 1024, 0, stream>>>(degi, incl, bsum, NN);
    k_scan3<<<(NN + 255) / 256, 256, 0, stream>>>(incl, degi, bsum, dis, rowstart, NN, EE, nsb);
    k_fill<<<(EE + 255) / 256, 256, 0, stream>>>(srcE, dstE, rowstart, fillc, colx, EE);
    k_prepw8<<<512, 256, 0, stream>>>(pre_w1, pre_w2, conv_w, conv_w + 16384,
                                      ffnn_w1, ffnn_w1 + 16384, ffnn_w2, ffnn_w2 + 16384, Wt);

    const int gB = (NN + 63) / 64;
    const float invN = 1.0f / NN;
    // preprocess FFNN + conv0 (dis-prescaled)
    k_mm<<<gB, 256, 0, stream>>>(x_in, nullptr, Wt + 0 * 16384, pre_b1, Wt + 1 * 16384, pre_b2,
                                 Wt + 2 * 16384, dis, nullptr, nullptr, nullptr, nullptr,
                                 invN, 0, 0, xf32, hbf, nullptr, nullptr, NN);
    // hop 0
    k_agg<<<2048, 256, 0, stream>>>(hbf, rowstart, colx, dis, conv_b,
                                    xf32, zbf, bnstat, bnstat + 128, NN);
    k_mm<<<gB, 256, 0, stream>>>(nullptr, zbf, Wt + 4 * 16384, ffnn_b1, Wt + 6 * 16384, ffnn_b2,
                                 Wt + 3 * 16384, dis, bnstat, bnstat + 128, bn_gamma, bn_beta,
                                 invN, 1, 1, xf32, hbf, nullptr, nullptr, NN);
    // hop 1
    k_agg<<<2048, 256, 0, stream>>>(hbf, rowstart, colx, dis, conv_b + 128,
                                    xf32, zbf, bnstat + 256, bnstat + 384, NN);
    // final FFNN + fused graph-mean-pool (no x write-back needed)
    k_mm<<<gB, 256, 0, stream>>>(nullptr, zbf, Wt + 5 * 16384, ffnn_b1 + 128, Wt + 7 * 16384, ffnn_b2 + 128,
                                 nullptr, nullptr, bnstat + 256, bnstat + 384, bn_gamma + 128, bn_beta + 128,
                                 invN, 1, 1, nullptr, nullptr, batch, pooled, NN);
    // post FFNN
    k_post<<<GG, 128, 0, stream>>>(pooled, batch, post_w1, post_b1, post_w2, post_b2,
                                   (float*)d_out, NN, GG);
}

// Round 10
// 370.479 us; speedup vs baseline: 1.0309x; 1.0309x over previous
//
#include <hip/hip_runtime.h>
#include <hip/hip_bf16.h>
#include <math.h>

#define NN 50000
#define EE 800000
#define GG 256
#define FILLB ((EE + 255) / 256)

typedef short bf16x8 __attribute__((ext_vector_type(8)));
typedef float f32x4 __attribute__((ext_vector_type(4)));
typedef unsigned int u32x4 __attribute__((ext_vector_type(4)));

__device__ __forceinline__ unsigned short f2bf(float x) {
    __hip_bfloat16 h = __float2bfloat16(x);
    union { __hip_bfloat16 h; unsigned short u; } c; c.h = h; return c.u;
}
__device__ __forceinline__ float bf2f(unsigned short u) {
    union { unsigned int v; float f; } t; t.v = ((unsigned int)u) << 16; return t.f;
}
__device__ __forceinline__ float gelu_f(float v) {
    return 0.5f * v * (1.0f + erff(v * 0.70710678118654752f));
}
// XOR swizzle for [rows][128 bf16] LDS tiles (256B row stride)
__device__ __forceinline__ int swz(int row, int bytecol) {
    return row * 256 + (bytecol ^ ((row & 7) << 4));
}

// ---------------- graph prep ----------------
__global__ void k_deg(const int* __restrict__ dst, int* __restrict__ degi, int E) {
    int i = blockIdx.x * blockDim.x + threadIdx.x;
    if (i < E) atomicAdd(&degi[dst[i]], 1);
}
__global__ void k_scan1(const int* __restrict__ degi, int* __restrict__ incl,
                        int* __restrict__ bsum, int N) {
    __shared__ int sm[1024];
    int t = threadIdx.x, i = blockIdx.x * 1024 + t;
    int v = (i < N) ? degi[i] : 0;
    sm[t] = v;
    __syncthreads();
    for (int off = 1; off < 1024; off <<= 1) {
        int add = (t >= off) ? sm[t - off] : 0;
        __syncthreads();
        sm[t] += add;
        __syncthreads();
    }
    if (i < N) incl[i] = sm[t];
    if (t == 1023) bsum[blockIdx.x] = sm[t];
}
// rowstart = exclusive scan (block offset via wave-reduce over bsum) ; + dis
__global__ void k_scan3(const int* __restrict__ incl, const int* __restrict__ degi,
                        const int* __restrict__ bsum, float* __restrict__ dis,
                        int* __restrict__ rowstart, int N, int E, int nsb) {
    __shared__ int sboff;
    int t = threadIdx.x;
    if (t < 64) {
        int nb = blockIdx.x >> 2;
        int v = (t < nb && t < nsb) ? bsum[t] : 0;
        #pragma unroll
        for (int o = 1; o < 64; o <<= 1) v += __shfl_xor(v, o, 64);
        if (t == 0) sboff = v;
    }
    __syncthreads();
    int i = blockIdx.x * 256 + t;
    if (i < N) {
        rowstart[i] = incl[i] - degi[i] + sboff;
        dis[i] = rsqrtf((float)(degi[i] + 1)); // +1 self loop
    }
    if (i == 0) rowstart[N] = E;
}
// merged: CSR fill (blocks 0..FILLB-1) + weight prep (blocks FILLB..FILLB+511)
__global__ void k_fillprep(const int* __restrict__ src, const int* __restrict__ dst,
                           const int* __restrict__ rowstart, int* __restrict__ fillc,
                           int* __restrict__ col,
                           const float* __restrict__ w0, const float* __restrict__ w1,
                           const float* __restrict__ w2, const float* __restrict__ w3,
                           const float* __restrict__ w4, const float* __restrict__ w5,
                           const float* __restrict__ w6, const float* __restrict__ w7,
                           unsigned short* __restrict__ Wt, int E) {
    int blk = blockIdx.x;
    if (blk < FILLB) {
        int i = blk * 256 + threadIdx.x;
        if (i < E) {
            int s = src[i], d = dst[i];
            int pos = rowstart[d] + atomicAdd(&fillc[d], 1);
            col[pos] = s;
        }
    } else {
        int b = (blk - FILLB) >> 6;
        const float* W = b == 0 ? w0 : b == 1 ? w1 : b == 2 ? w2 : b == 3 ? w3
                       : b == 4 ? w4 : b == 5 ? w5 : b == 6 ? w6 : w7;
        int tid = ((blk - FILLB) & 63) * 256 + threadIdx.x;
        int n = tid >> 7, k = tid & 127;
        *(unsigned short*)((char*)(Wt + (size_t)b * 16384) + swz(n, k * 2)) = f2bf(W[k * 128 + n]);
    }
}

// ---------------- fused 3-matmul chain ----------------
// x' = [BN](A); h = gelu(x'@W1+b1); y = h@W2+b2 [+ x' residual] -> outxbf /
// fused graph-pool; optional stage3: out3 = bf16(dis[row] * (y@W3)).
__global__ __launch_bounds__(256) void k_mm(
    const float* __restrict__ A32, const unsigned short* __restrict__ A16,
    const unsigned short* __restrict__ W1, const float* __restrict__ b1,
    const unsigned short* __restrict__ W2, const float* __restrict__ b2,
    const unsigned short* __restrict__ W3, const float* __restrict__ disv,
    const float* __restrict__ st_sum, const float* __restrict__ st_sq,
    const float* __restrict__ st_g, const float* __restrict__ st_b,
    float invN, int bn, int hasres,
    unsigned short* __restrict__ outxbf, unsigned short* __restrict__ out3,
    const int* __restrict__ batch, float* __restrict__ pooled, int M)
{
    __shared__ unsigned short As[64 * 128];
    __shared__ unsigned short Ws[128 * 128];
    __shared__ float lsc[128], lsh[128];
    __shared__ float sdis[64];
    __shared__ int gid[64];
    const int tid = threadIdx.x;
    const int bm = blockIdx.x * 64;
    if (st_sum && tid < 128) {
        float m = st_sum[tid] * invN;
        float var = st_sq[tid] * invN - m * m;
        float s = st_g[tid] * rsqrtf(var + 1e-5f);
        lsc[tid] = s;
        lsh[tid] = st_b[tid] - m * s;
    }
    __syncthreads();
    { // stage W1
        const uint4* srcp = (const uint4*)W1;
        uint4* dstp = (uint4*)Ws;
        for (int i = tid; i < 2048; i += 256) dstp[i] = srcp[i];
    }
    // stage A, 4 passes of 16 rows; optional BN affine
    #pragma unroll
    for (int pass = 0; pass < 4; ++pass) {
        int row = pass * 16 + (tid >> 4);
        int c8 = tid & 15;
        int gr = bm + row; if (gr > M - 1) gr = M - 1;
        float vv[8];
        if (A32) {
            const float* pp = A32 + (size_t)gr * 128 + c8 * 8;
            float4 v0 = *(const float4*)pp;
            float4 v1 = *(const float4*)(pp + 4);
            vv[0] = v0.x; vv[1] = v0.y; vv[2] = v0.z; vv[3] = v0.w;
            vv[4] = v1.x; vv[5] = v1.y; vv[6] = v1.z; vv[7] = v1.w;
        } else {
            u32x4 raw = __builtin_nontemporal_load((const u32x4*)(A16 + (size_t)gr * 128 + c8 * 8));
            #pragma unroll
            for (int d = 0; d < 4; ++d) {
                vv[2 * d]     = bf2f((unsigned short)(raw[d] & 0xffff));
                vv[2 * d + 1] = bf2f((unsigned short)(raw[d] >> 16));
            }
        }
        if (bn) {
            int ch = c8 * 8;
            #pragma unroll
            for (int j = 0; j < 8; ++j) vv[j] = vv[j] * lsc[ch + j] + lsh[ch + j];
        }
        unsigned short tmp[8];
        #pragma unroll
        for (int j = 0; j < 8; ++j) tmp[j] = f2bf(vv[j]);
        *(uint4*)((char*)As + swz(row, c8 * 16)) = *(uint4*)tmp;
    }
    __syncthreads();

    const int lane = tid & 63, wid = tid >> 6;
    const int r0 = wid * 16;
    const int lrow = lane & 15;
    const int lkb = (lane >> 4) * 16;
    const int cb = lane & 15;
    const int rb = r0 + (lane >> 4) * 4;

    f32x4 acc[8];
    // ---- mm1 ----
    #pragma unroll
    for (int n = 0; n < 8; ++n) acc[n] = (f32x4){0.f, 0.f, 0.f, 0.f};
    #pragma unroll
    for (int kk = 0; kk < 4; ++kk) {
        int bc = kk * 64 + lkb;
        bf16x8 a = *(const bf16x8*)((const char*)As + swz(r0 + lrow, bc));
        #pragma unroll
        for (int n = 0; n < 8; ++n) {
            bf16x8 b = *(const bf16x8*)((const char*)Ws + swz(n * 16 + lrow, bc));
            acc[n] = __builtin_amdgcn_mfma_f32_16x16x32_bf16(a, b, acc[n], 0, 0, 0);
        }
    }
    // capture residual x' (BN'd A) from own epilogue slots BEFORE epi1 overwrites
    unsigned short rres[32];
    if (hasres) {
        #pragma unroll
        for (int n = 0; n < 8; ++n)
            #pragma unroll
            for (int j = 0; j < 4; ++j)
                rres[n * 4 + j] = *(const unsigned short*)((const char*)As + swz(rb + j, (n * 16 + cb) * 2));
    }
    // epi1: gelu -> h into own As slab (rows rb..rb+3 are wave-private)
    #pragma unroll
    for (int n = 0; n < 8; ++n) {
        int colg = n * 16 + cb;
        float bv = b1[colg];
        #pragma unroll
        for (int j = 0; j < 4; ++j) {
            float v = gelu_f(acc[n][j] + bv);
            *(unsigned short*)((char*)As + swz(rb + j, colg * 2)) = f2bf(v);
        }
    }
    __syncthreads(); // all waves done reading W1
    { // stage W2
        const uint4* srcp = (const uint4*)W2;
        uint4* dstp = (uint4*)Ws;
        for (int i = tid; i < 2048; i += 256) dstp[i] = srcp[i];
    }
    __syncthreads();
    // ---- mm2 ----
    #pragma unroll
    for (int n = 0; n < 8; ++n) acc[n] = (f32x4){0.f, 0.f, 0.f, 0.f};
    #pragma unroll
    for (int kk = 0; kk < 4; ++kk) {
        int bc = kk * 64 + lkb;
        bf16x8 a = *(const bf16x8*)((const char*)As + swz(r0 + lrow, bc));
        #pragma unroll
        for (int n = 0; n < 8; ++n) {
            bf16x8 b = *(const bf16x8*)((const char*)Ws + swz(n * 16 + lrow, bc));
            acc[n] = __builtin_amdgcn_mfma_f32_16x16x32_bf16(a, b, acc[n], 0, 0, 0);
        }
    }
    const int dopool = (pooled != nullptr);
    // epi2: final v kept in acc; bf16 out / As for stage3
    #pragma unroll
    for (int n = 0; n < 8; ++n) {
        int colg = n * 16 + cb;
        float bv = b2[colg];
        #pragma unroll
        for (int j = 0; j < 4; ++j) {
            int rowg = bm + rb + j;
            float v = acc[n][j] + bv;
            if (hasres) v += bf2f(rres[n * 4 + j]);
            acc[n][j] = v;
            if (outxbf && rowg < M) outxbf[(size_t)rowg * 128 + colg] = f2bf(v);
            if (W3) *(unsigned short*)((char*)As + swz(rb + j, colg * 2)) = f2bf(v);
        }
    }
    if (dopool) {
        __syncthreads(); // ALL waves done reading W2 before Ws is reused as fp32 staging
        float* wsf = (float*)Ws;
        #pragma unroll
        for (int n = 0; n < 8; ++n)
            #pragma unroll
            for (int j = 0; j < 4; ++j)
                wsf[(rb + j) * 128 + n * 16 + cb] = acc[n][j];
        if (tid < 64) { int r = bm + tid; gid[tid] = (r < M) ? batch[r] : -1; }
        __syncthreads();
        if (tid < 128) {
            float pacc = 0.f;
            int gcur = gid[0];
            #pragma unroll 4
            for (int r = 0; r < 64; ++r) {
                int gg = gid[r];
                if (gg != gcur) {
                    if (gcur >= 0) atomicAdd(&pooled[(size_t)gcur * 128 + tid], pacc);
                    pacc = 0.f; gcur = gg;
                }
                if (gg >= 0) pacc += wsf[r * 128 + tid];
            }
            if (gcur >= 0) atomicAdd(&pooled[(size_t)gcur * 128 + tid], pacc);
        }
        return;
    }
    if (!W3) return;
    __syncthreads(); // all waves done reading W2
    { // stage W3 + dis slice
        const uint4* srcp = (const uint4*)W3;
        uint4* dstp = (uint4*)Ws;
        for (int i = tid; i < 2048; i += 256) dstp[i] = srcp[i];
        if (tid < 64) { int r = bm + tid; sdis[tid] = disv[(r < M) ? r : (M - 1)]; }
    }
    __syncthreads();
    // ---- mm3 (conv, pre-scaled by dis[row]) ----
    #pragma unroll
    for (int n = 0; n < 8; ++n) acc[n] = (f32x4){0.f, 0.f, 0.f, 0.f};
    #pragma unroll
    for (int kk = 0; kk < 4; ++kk) {
        int bc = kk * 64 + lkb;
        bf16x8 a = *(const bf16x8*)((const char*)As + swz(r0 + lrow, bc));
        #pragma unroll
        for (int n = 0; n < 8; ++n) {
            bf16x8 b = *(const bf16x8*)((const char*)Ws + swz(n * 16 + lrow, bc));
            acc[n] = __builtin_amdgcn_mfma_f32_16x16x32_bf16(a, b, acc[n], 0, 0, 0);
        }
    }
    #pragma unroll
    for (int n = 0; n < 8; ++n) {
        int colg = n * 16 + cb;
        #pragma unroll
        for (int j = 0; j < 4; ++j) {
            int rowg = bm + rb + j;
            if (rowg < M) out3[(size_t)rowg * 128 + colg] = f2bf(acc[n][j] * sdis[rb + j]);
        }
    }
}

// ---------------- CSR aggregation (unweighted sum of dis-prescaled rows) ----------------
// z_v = dis_v * (sum_u xws_u + xws_v) + conv_b + x_v ; BN partial stats.
// Finalize inputs (dis, self row, x residual) hoisted before the edge loop.
__global__ __launch_bounds__(256) void k_agg(
    const unsigned short* __restrict__ xws, const int* __restrict__ rowstart,
    const int* __restrict__ col,
    const float* __restrict__ dis, const float* __restrict__ convb,
    const unsigned short* __restrict__ x0, unsigned short* __restrict__ zbf,
    float* __restrict__ bnsum, float* __restrict__ bnsq, int N)
{
    __shared__ float redS[4][128];
    __shared__ float redQ[4][128];
    const int tid = threadIdx.x;
    const int lane = tid & 63;
    const int wid = tid >> 6;
    const int g = lane >> 4;
    const int cl = lane & 15;
    const int ch = cl * 8;
    const int wave = blockIdx.x * 4 + wid;
    const int nwaves = gridDim.x * 4;

    float cb[8];
    #pragma unroll
    for (int j = 0; j < 8; ++j) cb[j] = convb[ch + j];
    float s[8], q[8];
    #pragma unroll
    for (int j = 0; j < 8; ++j) { s[j] = 0.f; q[j] = 0.f; }

    for (int v = wave; v < N; v += nwaves) {
        const int e0 = rowstart[v], e1 = rowstart[v + 1];
        // hoist finalize loads: latency hides under the edge loop
        float dv = 0.f;
        u32x4 pself = (u32x4){0, 0, 0, 0};
        u32x4 x16 = (u32x4){0, 0, 0, 0};
        if (g == 0) {
            dv = dis[v];
            pself = *(const u32x4*)(xws + (size_t)v * 128 + ch);
            x16 = __builtin_nontemporal_load((const u32x4*)(x0 + (size_t)v * 128 + ch));
        }
        float a[8];
        #pragma unroll
        for (int j = 0; j < 8; ++j) a[j] = 0.f;
        int e = e0 + g;
        // 4-wide: 4 independent gathers in flight per iteration (16 edges/wave)
        for (; e + 12 < e1; e += 16) {
            const int u0 = col[e];
            const int u1 = col[e + 4];
            const int u2 = col[e + 8];
            const int u3 = col[e + 12];
            u32x4 p0 = *(const u32x4*)(xws + (size_t)u0 * 128 + ch);
            u32x4 p1 = *(const u32x4*)(xws + (size_t)u1 * 128 + ch);
            u32x4 p2 = *(const u32x4*)(xws + (size_t)u2 * 128 + ch);
            u32x4 p3 = *(const u32x4*)(xws + (size_t)u3 * 128 + ch);
            #pragma unroll
            for (int d = 0; d < 4; ++d) {
                a[2 * d]     += bf2f((unsigned short)(p0[d] & 0xffff)) + bf2f((unsigned short)(p1[d] & 0xffff))
                              + bf2f((unsigned short)(p2[d] & 0xffff)) + bf2f((unsigned short)(p3[d] & 0xffff));
                a[2 * d + 1] += bf2f((unsigned short)(p0[d] >> 16)) + bf2f((unsigned short)(p1[d] >> 16))
                              + bf2f((unsigned short)(p2[d] >> 16)) + bf2f((unsigned short)(p3[d] >> 16));
            }
        }
        for (; e + 4 < e1; e += 8) {
            const int u0 = col[e];
            const int u1 = col[e + 4];
            u32x4 p0 = *(const u32x4*)(xws + (size_t)u0 * 128 + ch);
            u32x4 p1 = *(const u32x4*)(xws + (size_t)u1 * 128 + ch);
            #pragma unroll
            for (int d = 0; d < 4; ++d) {
                a[2 * d]     += bf2f((unsigned short)(p0[d] & 0xffff)) + bf2f((unsigned short)(p1[d] & 0xffff));
                a[2 * d + 1] += bf2f((unsigned short)(p0[d] >> 16)) + bf2f((unsigned short)(p1[d] >> 16));
            }
        }
        if (e < e1) {
            const int u = col[e];
            u32x4 p = *(const u32x4*)(xws + (size_t)u * 128 + ch);
            #pragma unroll
            for (int d = 0; d < 4; ++d) {
                a[2 * d]     += bf2f((unsigned short)(p[d] & 0xffff));
                a[2 * d + 1] += bf2f((unsigned short)(p[d] >> 16));
            }
        }
        #pragma unroll
        for (int j = 0; j < 8; ++j) {
            a[j] += __shfl_xor(a[j], 16, 64);
            a[j] += __shfl_xor(a[j], 32, 64);
        }
        if (g == 0) {
            float zz[8];
            #pragma unroll
            for (int d = 0; d < 4; ++d) {
                zz[2 * d]     = dv * (a[2 * d]     + bf2f((unsigned short)(pself[d] & 0xffff)));
                zz[2 * d + 1] = dv * (a[2 * d + 1] + bf2f((unsigned short)(pself[d] >> 16)));
            }
            const float xr[8] = {
                bf2f((unsigned short)(x16[0] & 0xffff)), bf2f((unsigned short)(x16[0] >> 16)),
                bf2f((unsigned short)(x16[1] & 0xffff)), bf2f((unsigned short)(x16[1] >> 16)),
                bf2f((unsigned short)(x16[2] & 0xffff)), bf2f((unsigned short)(x16[2] >> 16)),
                bf2f((unsigned short)(x16[3] & 0xffff)), bf2f((unsigned short)(x16[3] >> 16))
            };
            unsigned short zo[8];
            #pragma unroll
            for (int j = 0; j < 8; ++j) {
                zz[j] += cb[j] + xr[j];
                s[j] += zz[j];
                q[j] += zz[j] * zz[j];
                zo[j] = f2bf(zz[j]);
            }
            __builtin_nontemporal_store(*(const u32x4*)zo, (u32x4*)(zbf + (size_t)v * 128 + ch));
        }
    }
    if (g == 0) {
        #pragma unroll
        for (int j = 0; j < 8; ++j) { redS[wid][ch + j] = s[j]; redQ[wid][ch + j] = q[j]; }
    }
    __syncthreads();
    if (tid < 128) {
        float ts = redS[0][tid] + redS[1][tid] + redS[2][tid] + redS[3][tid];
        float tq = redQ[0][tid] + redQ[1][tid] + redQ[2][tid] + redQ[3][tid];
        atomicAdd(&bnsum[tid], ts);
        atomicAdd(&bnsq[tid], tq);
    }
}
// post FFNN (exact fp32); per-graph counts via binary search over sorted batch
__global__ __launch_bounds__(128) void k_post(
    const float* __restrict__ pooled, const int* __restrict__ batch,
    const float* __restrict__ w1, const float* __restrict__ b1,
    const float* __restrict__ w2, const float* __restrict__ b2,
    float* __restrict__ out, int N, int G)
{
    __shared__ float pr[128], hr[128];
    __shared__ int bounds[2];
    int g = blockIdx.x, t = threadIdx.x;
    if (t < 2) {
        int tgt = g + t, lo = 0, hi = N;
        while (lo < hi) { int mid = (lo + hi) >> 1; if (batch[mid] < tgt) lo = mid + 1; else hi = mid; }
        bounds[t] = lo;
    }
    __syncthreads();
    float c = fmaxf((float)(bounds[1] - bounds[0]), 1.0f);
    pr[t] = pooled[(size_t)g * 128 + t] / c;
    __syncthreads();
    float a = b1[t];
    for (int k = 0; k < 128; ++k) a += pr[k] * w1[k * 128 + t];
    hr[t] = gelu_f(a);
    __syncthreads();
    if (t < 64) {
        float o = b2[t];
        for (int k = 0; k < 128; ++k) o += hr[k] * w2[k * 64 + t];
        out[g * 64 + t] = o;
    }
}

extern "C" void kernel_launch(void* const* d_in, const int* in_sizes, int n_in,
                              void* d_out, int out_size, void* d_ws, size_t ws_size,
                              hipStream_t stream) {
    (void)in_sizes; (void)n_in; (void)out_size; (void)ws_size;
    const float* x_in    = (const float*)d_in[0];
    const int*   ei      = (const int*)d_in[1];
    const int*   batch   = (const int*)d_in[2];
    const float* pre_w1  = (const float*)d_in[3];
    const float* pre_b1  = (const float*)d_in[4];
    const float* pre_w2  = (const float*)d_in[5];
    const float* pre_b2  = (const float*)d_in[6];
    const float* conv_w  = (const float*)d_in[7];
    const float* conv_b  = (const float*)d_in[8];
    const float* ffnn_w1 = (const float*)d_in[9];
    const float* ffnn_b1 = (const float*)d_in[10];
    const float* ffnn_w2 = (const float*)d_in[11];
    const float* ffnn_b2 = (const float*)d_in[12];
    const float* bn_gamma= (const float*)d_in[13];
    const float* bn_beta = (const float*)d_in[14];
    const float* post_w1 = (const float*)d_in[15];
    const float* post_b1 = (const float*)d_in[16];
    const float* post_w2 = (const float*)d_in[17];
    const float* post_b2 = (const float*)d_in[18];
    const int* srcE = ei;
    const int* dstE = ei + EE;

    char* base = (char*)d_ws;
    size_t off = 0;
    auto carve = [&](size_t bytes) {
        char* q = base + off;
        off = (off + bytes + 255) & ~(size_t)255;
        return q;
    };
    unsigned short* xbf = (unsigned short*)carve((size_t)NN * 128 * 2); // x residual (bf16)
    unsigned short* zbf = (unsigned short*)carve((size_t)NN * 128 * 2);
    unsigned short* hbf = (unsigned short*)carve((size_t)NN * 128 * 2); // xws scratch
    float* dis   = (float*)carve((size_t)NN * 4);
    // zero-region: degi, fillc, pooled, bnstat contiguous -> ONE memset
    int*   degi  = (int*)carve((size_t)NN * 4);
    int*   fillc = (int*)carve((size_t)NN * 4);
    float* pooled= (float*)carve((size_t)GG * 128 * 4);
    float* bnstat= (float*)carve(512 * 4); // [hop][sum|sq][128]
    size_t zlen  = (size_t)((char*)(bnstat + 512) - (char*)degi);
    int* incl    = (int*)carve((size_t)NN * 4);
    int* bsum    = (int*)carve(64 * 4);
    int* rowstart= (int*)carve((size_t)(NN + 1) * 4);
    int* colx    = (int*)carve((size_t)EE * 4);
    unsigned short* Wt = (unsigned short*)carve((size_t)8 * 16384 * 2);

    hipMemsetAsync(degi, 0, zlen, stream);

    const int nsb = (NN + 1023) / 1024;
    k_deg<<<(EE + 255) / 256, 256, 0, stream>>>(dstE, degi, EE);
    k_scan1<<<nsb, 1024, 0, stream>>>(degi, incl, bsum, NN);
    k_scan3<<<(NN + 255) / 256, 256, 0, stream>>>(incl, degi, bsum, dis, rowstart, NN, EE, nsb);
    k_fillprep<<<FILLB + 512, 256, 0, stream>>>(srcE, dstE, rowstart, fillc, colx,
                                                pre_w1, pre_w2, conv_w, conv_w + 16384,
                                                ffnn_w1, ffnn_w1 + 16384, ffnn_w2, ffnn_w2 + 16384,
                                                Wt, EE);

    const int gB = (NN + 63) / 64;
    const float invN = 1.0f / NN;
    // preprocess FFNN + conv0 (dis-prescaled)
    k_mm<<<gB, 256, 0, stream>>>(x_in, nullptr, Wt + 0 * 16384, pre_b1, Wt + 1 * 16384, pre_b2,
                                 Wt + 2 * 16384, dis, nullptr, nullptr, nullptr, nullptr,
                                 invN, 0, 0, xbf, hbf, nullptr, nullptr, NN);
    // hop 0
    k_agg<<<2048, 256, 0, stream>>>(hbf, rowstart, colx, dis, conv_b,
                                    xbf, zbf, bnstat, bnstat + 128, NN);
    k_mm<<<gB, 256, 0, stream>>>(nullptr, zbf, Wt + 4 * 16384, ffnn_b1, Wt + 6 * 16384, ffnn_b2,
                                 Wt + 3 * 16384, dis, bnstat, bnstat + 128, bn_gamma, bn_beta,
                                 invN, 1, 1, xbf, hbf, nullptr, nullptr, NN);
    // hop 1
    k_agg<<<2048, 256, 0, stream>>>(hbf, rowstart, colx, dis, conv_b + 128,
                                    xbf, zbf, bnstat + 256, bnstat + 384, NN);
    // final FFNN + fused graph-mean-pool
    k_mm<<<gB, 256, 0, stream>>>(nullptr, zbf, Wt + 5 * 16384, ffnn_b1 + 128, Wt + 7 * 16384, ffnn_b2 + 128,
                                 nullptr, nullptr, bnstat + 256, bnstat + 384, bn_gamma + 128, bn_beta + 128,
                                 invN, 1, 1, nullptr, nullptr, batch, pooled, NN);
    // post FFNN
    k_post<<<GG, 128, 0, stream>>>(pooled, batch, post_w1, post_b1, post_w2, post_b2,
                                   (float*)d_out, NN, GG);
}

// Round 11
// 334.379 us; speedup vs baseline: 1.1422x; 1.1080x over previous
//
#include <hip/hip_runtime.h>
#include <hip/hip_bf16.h>
#include <math.h>

#define NN 50000
#define EE 800000
#define GG 256
#define FILLB ((EE + 255) / 256)

typedef short bf16x8 __attribute__((ext_vector_type(8)));
typedef float f32x4 __attribute__((ext_vector_type(4)));
typedef unsigned int u32x4 __attribute__((ext_vector_type(4)));

__device__ __forceinline__ unsigned short f2bf(float x) {
    __hip_bfloat16 h = __float2bfloat16(x);
    union { __hip_bfloat16 h; unsigned short u; } c; c.h = h; return c.u;
}
__device__ __forceinline__ float bf2f(unsigned short u) {
    union { unsigned int v; float f; } t; t.v = ((unsigned int)u) << 16; return t.f;
}
__device__ __forceinline__ float gelu_f(float v) {
    return 0.5f * v * (1.0f + erff(v * 0.70710678118654752f));
}
// XOR swizzle for [rows][128 bf16] LDS tiles (256B row stride)
__device__ __forceinline__ int swz(int row, int bytecol) {
    return row * 256 + (bytecol ^ ((row & 7) << 4));
}

// ---------------- graph prep ----------------
__global__ void k_deg(const int* __restrict__ dst, int* __restrict__ degi, int E) {
    int i = blockIdx.x * blockDim.x + threadIdx.x;
    if (i < E) atomicAdd(&degi[dst[i]], 1);
}
__global__ void k_scan1(const int* __restrict__ degi, int* __restrict__ incl,
                        int* __restrict__ bsum, int N) {
    __shared__ int sm[1024];
    int t = threadIdx.x, i = blockIdx.x * 1024 + t;
    int v = (i < N) ? degi[i] : 0;
    sm[t] = v;
    __syncthreads();
    for (int off = 1; off < 1024; off <<= 1) {
        int add = (t >= off) ? sm[t - off] : 0;
        __syncthreads();
        sm[t] += add;
        __syncthreads();
    }
    if (i < N) incl[i] = sm[t];
    if (t == 1023) bsum[blockIdx.x] = sm[t];
}
// rowstart = exclusive scan (block offset via wave-reduce over bsum) ; + dis
__global__ void k_scan3(const int* __restrict__ incl, const int* __restrict__ degi,
                        const int* __restrict__ bsum, float* __restrict__ dis,
                        int* __restrict__ rowstart, int N, int E, int nsb) {
    __shared__ int sboff;
    int t = threadIdx.x;
    if (t < 64) {
        int nb = blockIdx.x >> 2;
        int v = (t < nb && t < nsb) ? bsum[t] : 0;
        #pragma unroll
        for (int o = 1; o < 64; o <<= 1) v += __shfl_xor(v, o, 64);
        if (t == 0) sboff = v;
    }
    __syncthreads();
    int i = blockIdx.x * 256 + t;
    if (i < N) {
        rowstart[i] = incl[i] - degi[i] + sboff;
        dis[i] = rsqrtf((float)(degi[i] + 1)); // +1 self loop
    }
    if (i == 0) rowstart[N] = E;
}
// merged: CSR fill (blocks 0..FILLB-1) + weight prep (blocks FILLB..FILLB+511)
__global__ void k_fillprep(const int* __restrict__ src, const int* __restrict__ dst,
                           const int* __restrict__ rowstart, int* __restrict__ fillc,
                           int* __restrict__ col,
                           const float* __restrict__ w0, const float* __restrict__ w1,
                           const float* __restrict__ w2, const float* __restrict__ w3,
                           const float* __restrict__ w4, const float* __restrict__ w5,
                           const float* __restrict__ w6, const float* __restrict__ w7,
                           unsigned short* __restrict__ Wt, int E) {
    int blk = blockIdx.x;
    if (blk < FILLB) {
        int i = blk * 256 + threadIdx.x;
        if (i < E) {
            int s = src[i], d = dst[i];
            int pos = rowstart[d] + atomicAdd(&fillc[d], 1);
            col[pos] = s;
        }
    } else {
        int b = (blk - FILLB) >> 6;
        const float* W = b == 0 ? w0 : b == 1 ? w1 : b == 2 ? w2 : b == 3 ? w3
                       : b == 4 ? w4 : b == 5 ? w5 : b == 6 ? w6 : w7;
        int tid = ((blk - FILLB) & 63) * 256 + threadIdx.x;
        int n = tid >> 7, k = tid & 127;
        *(unsigned short*)((char*)(Wt + (size_t)b * 16384) + swz(n, k * 2)) = f2bf(W[k * 128 + n]);
    }
}

// ---------------- fused 3-matmul chain (128-row tile, 512 threads) ----------------
// x' = [BN](A); h = gelu(x'@W1+b1); y = h@W2+b2 [+ x' residual] -> outxbf /
// fused graph-pool; optional stage3: out3 = bf16(dis[row] * (y@W3)).
__global__ __launch_bounds__(512) void k_mm(
    const float* __restrict__ A32, const unsigned short* __restrict__ A16,
    const unsigned short* __restrict__ W1, const float* __restrict__ b1,
    const unsigned short* __restrict__ W2, const float* __restrict__ b2,
    const unsigned short* __restrict__ W3, const float* __restrict__ disv,
    const float* __restrict__ st_sum, const float* __restrict__ st_sq,
    const float* __restrict__ st_g, const float* __restrict__ st_b,
    float invN, int bn, int hasres,
    unsigned short* __restrict__ outxbf, unsigned short* __restrict__ out3,
    const int* __restrict__ batch, float* __restrict__ pooled, int M)
{
    __shared__ unsigned short As[128 * 128];
    __shared__ unsigned short Ws[128 * 128];
    __shared__ float lsc[128], lsh[128];
    __shared__ float sdis[128];
    __shared__ int gid[128];
    const int tid = threadIdx.x;
    const int bm = blockIdx.x * 128;
    if (st_sum && tid < 128) {
        float m = st_sum[tid] * invN;
        float var = st_sq[tid] * invN - m * m;
        float s = st_g[tid] * rsqrtf(var + 1e-5f);
        lsc[tid] = s;
        lsh[tid] = st_b[tid] - m * s;
    }
    __syncthreads();
    { // stage W1
        const uint4* srcp = (const uint4*)W1;
        uint4* dstp = (uint4*)Ws;
        for (int i = tid; i < 2048; i += 512) dstp[i] = srcp[i];
    }
    // stage A, 4 passes of 32 rows; optional BN affine
    #pragma unroll
    for (int pass = 0; pass < 4; ++pass) {
        int row = pass * 32 + (tid >> 4);
        int c8 = tid & 15;
        int gr = bm + row; if (gr > M - 1) gr = M - 1;
        float vv[8];
        if (A32) {
            const float* pp = A32 + (size_t)gr * 128 + c8 * 8;
            float4 v0 = *(const float4*)pp;
            float4 v1 = *(const float4*)(pp + 4);
            vv[0] = v0.x; vv[1] = v0.y; vv[2] = v0.z; vv[3] = v0.w;
            vv[4] = v1.x; vv[5] = v1.y; vv[6] = v1.z; vv[7] = v1.w;
        } else {
            u32x4 raw = __builtin_nontemporal_load((const u32x4*)(A16 + (size_t)gr * 128 + c8 * 8));
            #pragma unroll
            for (int d = 0; d < 4; ++d) {
                vv[2 * d]     = bf2f((unsigned short)(raw[d] & 0xffff));
                vv[2 * d + 1] = bf2f((unsigned short)(raw[d] >> 16));
            }
        }
        if (bn) {
            int ch = c8 * 8;
            #pragma unroll
            for (int j = 0; j < 8; ++j) vv[j] = vv[j] * lsc[ch + j] + lsh[ch + j];
        }
        unsigned short tmp[8];
        #pragma unroll
        for (int j = 0; j < 8; ++j) tmp[j] = f2bf(vv[j]);
        *(uint4*)((char*)As + swz(row, c8 * 16)) = *(uint4*)tmp;
    }
    __syncthreads();

    const int lane = tid & 63, wid = tid >> 6; // 8 waves, 16 rows each
    const int r0 = wid * 16;
    const int lrow = lane & 15;
    const int lkb = (lane >> 4) * 16;
    const int cb = lane & 15;
    const int rb = r0 + (lane >> 4) * 4;

    f32x4 acc[8];
    // ---- mm1 ----
    #pragma unroll
    for (int n = 0; n < 8; ++n) acc[n] = (f32x4){0.f, 0.f, 0.f, 0.f};
    #pragma unroll
    for (int kk = 0; kk < 4; ++kk) {
        int bc = kk * 64 + lkb;
        bf16x8 a = *(const bf16x8*)((const char*)As + swz(r0 + lrow, bc));
        #pragma unroll
        for (int n = 0; n < 8; ++n) {
            bf16x8 b = *(const bf16x8*)((const char*)Ws + swz(n * 16 + lrow, bc));
            acc[n] = __builtin_amdgcn_mfma_f32_16x16x32_bf16(a, b, acc[n], 0, 0, 0);
        }
    }
    // capture residual x' (BN'd A) from own epilogue slots BEFORE epi1 overwrites
    unsigned short rres[32];
    if (hasres) {
        #pragma unroll
        for (int n = 0; n < 8; ++n)
            #pragma unroll
            for (int j = 0; j < 4; ++j)
                rres[n * 4 + j] = *(const unsigned short*)((const char*)As + swz(rb + j, (n * 16 + cb) * 2));
    }
    // epi1: gelu -> h into own As slab (rows rb..rb+3 are wave-private)
    #pragma unroll
    for (int n = 0; n < 8; ++n) {
        int colg = n * 16 + cb;
        float bv = b1[colg];
        #pragma unroll
        for (int j = 0; j < 4; ++j) {
            float v = gelu_f(acc[n][j] + bv);
            *(unsigned short*)((char*)As + swz(rb + j, colg * 2)) = f2bf(v);
        }
    }
    __syncthreads(); // all waves done reading W1
    { // stage W2
        const uint4* srcp = (const uint4*)W2;
        uint4* dstp = (uint4*)Ws;
        for (int i = tid; i < 2048; i += 512) dstp[i] = srcp[i];
    }
    __syncthreads();
    // ---- mm2 ----
    #pragma unroll
    for (int n = 0; n < 8; ++n) acc[n] = (f32x4){0.f, 0.f, 0.f, 0.f};
    #pragma unroll
    for (int kk = 0; kk < 4; ++kk) {
        int bc = kk * 64 + lkb;
        bf16x8 a = *(const bf16x8*)((const char*)As + swz(r0 + lrow, bc));
        #pragma unroll
        for (int n = 0; n < 8; ++n) {
            bf16x8 b = *(const bf16x8*)((const char*)Ws + swz(n * 16 + lrow, bc));
            acc[n] = __builtin_amdgcn_mfma_f32_16x16x32_bf16(a, b, acc[n], 0, 0, 0);
        }
    }
    const int dopool = (pooled != nullptr);
    // epi2: final v kept in acc; bf16 out / As for stage3
    #pragma unroll
    for (int n = 0; n < 8; ++n) {
        int colg = n * 16 + cb;
        float bv = b2[colg];
        #pragma unroll
        for (int j = 0; j < 4; ++j) {
            int rowg = bm + rb + j;
            float v = acc[n][j] + bv;
            if (hasres) v += bf2f(rres[n * 4 + j]);
            acc[n][j] = v;
            if (outxbf && rowg < M) outxbf[(size_t)rowg * 128 + colg] = f2bf(v);
            if (W3) *(unsigned short*)((char*)As + swz(rb + j, colg * 2)) = f2bf(v);
        }
    }
    if (dopool) {
        __syncthreads(); // ALL waves done with As/Ws before reuse as fp32 staging
        // 128x128 fp32 staging: rows 0..63 in As (32KB), rows 64..127 in Ws (32KB)
        float* wsfA = (float*)As;
        float* wsfB = (float*)Ws;
        #pragma unroll
        for (int n = 0; n < 8; ++n)
            #pragma unroll
            for (int j = 0; j < 4; ++j) {
                int row = rb + j;
                float* dstrow = (row < 64) ? (wsfA + row * 128) : (wsfB + (row - 64) * 128);
                dstrow[n * 16 + cb] = acc[n][j];
            }
        if (tid < 128) { int r = bm + tid; gid[tid] = (r < M) ? batch[r] : -1; }
        __syncthreads();
        if (tid < 128) {
            float pacc = 0.f;
            int gcur = gid[0];
            for (int r = 0; r < 128; ++r) {
                int gg = gid[r];
                if (gg != gcur) {
                    if (gcur >= 0) atomicAdd(&pooled[(size_t)gcur * 128 + tid], pacc);
                    pacc = 0.f; gcur = gg;
                }
                if (gg >= 0) pacc += (r < 64) ? wsfA[r * 128 + tid] : wsfB[(r - 64) * 128 + tid];
            }
            if (gcur >= 0) atomicAdd(&pooled[(size_t)gcur * 128 + tid], pacc);
        }
        return;
    }
    if (!W3) return;
    __syncthreads(); // all waves done reading W2
    { // stage W3 + dis slice
        const uint4* srcp = (const uint4*)W3;
        uint4* dstp = (uint4*)Ws;
        for (int i = tid; i < 2048; i += 512) dstp[i] = srcp[i];
        if (tid < 128) { int r = bm + tid; sdis[tid] = disv[(r < M) ? r : (M - 1)]; }
    }
    __syncthreads();
    // ---- mm3 (conv, pre-scaled by dis[row]) ----
    #pragma unroll
    for (int n = 0; n < 8; ++n) acc[n] = (f32x4){0.f, 0.f, 0.f, 0.f};
    #pragma unroll
    for (int kk = 0; kk < 4; ++kk) {
        int bc = kk * 64 + lkb;
        bf16x8 a = *(const bf16x8*)((const char*)As + swz(r0 + lrow, bc));
        #pragma unroll
        for (int n = 0; n < 8; ++n) {
            bf16x8 b = *(const bf16x8*)((const char*)Ws + swz(n * 16 + lrow, bc));
            acc[n] = __builtin_amdgcn_mfma_f32_16x16x32_bf16(a, b, acc[n], 0, 0, 0);
        }
    }
    #pragma unroll
    for (int n = 0; n < 8; ++n) {
        int colg = n * 16 + cb;
        #pragma unroll
        for (int j = 0; j < 4; ++j) {
            int rowg = bm + rb + j;
            if (rowg < M) out3[(size_t)rowg * 128 + colg] = f2bf(acc[n][j] * sdis[rb + j]);
        }
    }
}

// ---------------- CSR aggregation (unweighted sum of dis-prescaled rows) ----------------
// z_v = dis_v * (sum_u xws_u + xws_v) + conv_b + x_v ; BN partial stats.
__global__ __launch_bounds__(256) void k_agg(
    const unsigned short* __restrict__ xws, const int* __restrict__ rowstart,
    const int* __restrict__ col,
    const float* __restrict__ dis, const float* __restrict__ convb,
    const unsigned short* __restrict__ x0, unsigned short* __restrict__ zbf,
    float* __restrict__ bnsum, float* __restrict__ bnsq, int N)
{
    __shared__ float redS[4][128];
    __shared__ float redQ[4][128];
    const int tid = threadIdx.x;
    const int lane = tid & 63;
    const int wid = tid >> 6;
    const int g = lane >> 4;
    const int cl = lane & 15;
    const int ch = cl * 8;
    const int wave = blockIdx.x * 4 + wid;
    const int nwaves = gridDim.x * 4;

    float cb[8];
    #pragma unroll
    for (int j = 0; j < 8; ++j) cb[j] = convb[ch + j];
    float s[8], q[8];
    #pragma unroll
    for (int j = 0; j < 8; ++j) { s[j] = 0.f; q[j] = 0.f; }

    for (int v = wave; v < N; v += nwaves) {
        const int e0 = rowstart[v], e1 = rowstart[v + 1];
        // hoist finalize loads: latency hides under the edge loop
        float dv = 0.f;
        u32x4 pself = (u32x4){0, 0, 0, 0};
        u32x4 x16 = (u32x4){0, 0, 0, 0};
        if (g == 0) {
            dv = dis[v];
            pself = *(const u32x4*)(xws + (size_t)v * 128 + ch);
            x16 = __builtin_nontemporal_load((const u32x4*)(x0 + (size_t)v * 128 + ch));
        }
        float a[8];
        #pragma unroll
        for (int j = 0; j < 8; ++j) a[j] = 0.f;
        int e = e0 + g;
        // 4-wide: 4 independent gathers in flight per iteration (16 edges/wave)
        for (; e + 12 < e1; e += 16) {
            const int u0 = col[e];
            const int u1 = col[e + 4];
            const int u2 = col[e + 8];
            const int u3 = col[e + 12];
            u32x4 p0 = *(const u32x4*)(xws + (size_t)u0 * 128 + ch);
            u32x4 p1 = *(const u32x4*)(xws + (size_t)u1 * 128 + ch);
            u32x4 p2 = *(const u32x4*)(xws + (size_t)u2 * 128 + ch);
            u32x4 p3 = *(const u32x4*)(xws + (size_t)u3 * 128 + ch);
            #pragma unroll
            for (int d = 0; d < 4; ++d) {
                a[2 * d]     += bf2f((unsigned short)(p0[d] & 0xffff)) + bf2f((unsigned short)(p1[d] & 0xffff))
                              + bf2f((unsigned short)(p2[d] & 0xffff)) + bf2f((unsigned short)(p3[d] & 0xffff));
                a[2 * d + 1] += bf2f((unsigned short)(p0[d] >> 16)) + bf2f((unsigned short)(p1[d] >> 16))
                              + bf2f((unsigned short)(p2[d] >> 16)) + bf2f((unsigned short)(p3[d] >> 16));
            }
        }
        for (; e + 4 < e1; e += 8) {
            const int u0 = col[e];
            const int u1 = col[e + 4];
            u32x4 p0 = *(const u32x4*)(xws + (size_t)u0 * 128 + ch);
            u32x4 p1 = *(const u32x4*)(xws + (size_t)u1 * 128 + ch);
            #pragma unroll
            for (int d = 0; d < 4; ++d) {
                a[2 * d]     += bf2f((unsigned short)(p0[d] & 0xffff)) + bf2f((unsigned short)(p1[d] & 0xffff));
                a[2 * d + 1] += bf2f((unsigned short)(p0[d] >> 16)) + bf2f((unsigned short)(p1[d] >> 16));
            }
        }
        if (e < e1) {
            const int u = col[e];
            u32x4 p = *(const u32x4*)(xws + (size_t)u * 128 + ch);
            #pragma unroll
            for (int d = 0; d < 4; ++d) {
                a[2 * d]     += bf2f((unsigned short)(p[d] & 0xffff));
                a[2 * d + 1] += bf2f((unsigned short)(p[d] >> 16));
            }
        }
        #pragma unroll
        for (int j = 0; j < 8; ++j) {
            a[j] += __shfl_xor(a[j], 16, 64);
            a[j] += __shfl_xor(a[j], 32, 64);
        }
        if (g == 0) {
            float zz[8];
            #pragma unroll
            for (int d = 0; d < 4; ++d) {
                zz[2 * d]     = dv * (a[2 * d]     + bf2f((unsigned short)(pself[d] & 0xffff)));
                zz[2 * d + 1] = dv * (a[2 * d + 1] + bf2f((unsigned short)(pself[d] >> 16)));
            }
            const float xr[8] = {
                bf2f((unsigned short)(x16[0] & 0xffff)), bf2f((unsigned short)(x16[0] >> 16)),
                bf2f((unsigned short)(x16[1] & 0xffff)), bf2f((unsigned short)(x16[1] >> 16)),
                bf2f((unsigned short)(x16[2] & 0xffff)), bf2f((unsigned short)(x16[2] >> 16)),
                bf2f((unsigned short)(x16[3] & 0xffff)), bf2f((unsigned short)(x16[3] >> 16))
            };
            unsigned short zo[8];
            #pragma unroll
            for (int j = 0; j < 8; ++j) {
                zz[j] += cb[j] + xr[j];
                s[j] += zz[j];
                q[j] += zz[j] * zz[j];
                zo[j] = f2bf(zz[j]);
            }
            __builtin_nontemporal_store(*(const u32x4*)zo, (u32x4*)(zbf + (size_t)v * 128 + ch));
        }
    }
    if (g == 0) {
        #pragma unroll
        for (int j = 0; j < 8; ++j) { redS[wid][ch + j] = s[j]; redQ[wid][ch + j] = q[j]; }
    }
    __syncthreads();
    if (tid < 128) {
        float ts = redS[0][tid] + redS[1][tid] + redS[2][tid] + redS[3][tid];
        float tq = redQ[0][tid] + redQ[1][tid] + redQ[2][tid] + redQ[3][tid];
        atomicAdd(&bnsum[tid], ts);
        atomicAdd(&bnsq[tid], tq);
    }
}
// post FFNN (exact fp32); per-graph counts via binary search over sorted batch
__global__ __launch_bounds__(128) void k_post(
    const float* __restrict__ pooled, const int* __restrict__ batch,
    const float* __restrict__ w1, const float* __restrict__ b1,
    const float* __restrict__ w2, const float* __restrict__ b2,
    float* __restrict__ out, int N, int G)
{
    __shared__ float pr[128], hr[128];
    __shared__ int bounds[2];
    int g = blockIdx.x, t = threadIdx.x;
    if (t < 2) {
        int tgt = g + t, lo = 0, hi = N;
        while (lo < hi) { int mid = (lo + hi) >> 1; if (batch[mid] < tgt) lo = mid + 1; else hi = mid; }
        bounds[t] = lo;
    }
    __syncthreads();
    float c = fmaxf((float)(bounds[1] - bounds[0]), 1.0f);
    pr[t] = pooled[(size_t)g * 128 + t] / c;
    __syncthreads();
    float a = b1[t];
    for (int k = 0; k < 128; ++k) a += pr[k] * w1[k * 128 + t];
    hr[t] = gelu_f(a);
    __syncthreads();
    if (t < 64) {
        float o = b2[t];
        for (int k = 0; k < 128; ++k) o += hr[k] * w2[k * 64 + t];
        out[g * 64 + t] = o;
    }
}

extern "C" void kernel_launch(void* const* d_in, const int* in_sizes, int n_in,
                              void* d_out, int out_size, void* d_ws, size_t ws_size,
                              hipStream_t stream) {
    (void)in_sizes; (void)n_in; (void)out_size; (void)ws_size;
    const float* x_in    = (const float*)d_in[0];
    const int*   ei      = (const int*)d_in[1];
    const int*   batch   = (const int*)d_in[2];
    const float* pre_w1  = (const float*)d_in[3];
    const float* pre_b1  = (const float*)d_in[4];
    const float* pre_w2  = (const float*)d_in[5];
    const float* pre_b2  = (const float*)d_in[6];
    const float* conv_w  = (const float*)d_in[7];
    const float* conv_b  = (const float*)d_in[8];
    const float* ffnn_w1 = (const float*)d_in[9];
    const float* ffnn_b1 = (const float*)d_in[10];
    const float* ffnn_w2 = (const float*)d_in[11];
    const float* ffnn_b2 = (const float*)d_in[12];
    const float* bn_gamma= (const float*)d_in[13];
    const float* bn_beta = (const float*)d_in[14];
    const float* post_w1 = (const float*)d_in[15];
    const float* post_b1 = (const float*)d_in[16];
    const float* post_w2 = (const float*)d_in[17];
    const float* post_b2 = (const float*)d_in[18];
    const int* srcE = ei;
    const int* dstE = ei + EE;

    char* base = (char*)d_ws;
    size_t off = 0;
    auto carve = [&](size_t bytes) {
        char* q = base + off;
        off = (off + bytes + 255) & ~(size_t)255;
        return q;
    };
    unsigned short* xbf = (unsigned short*)carve((size_t)NN * 128 * 2); // x residual (bf16)
    unsigned short* zbf = (unsigned short*)carve((size_t)NN * 128 * 2);
    unsigned short* hbf = (unsigned short*)carve((size_t)NN * 128 * 2); // xws scratch
    float* dis   = (float*)carve((size_t)NN * 4);
    // zero-region: degi, fillc, pooled, bnstat contiguous -> ONE memset
    int*   degi  = (int*)carve((size_t)NN * 4);
    int*   fillc = (int*)carve((size_t)NN * 4);
    float* pooled= (float*)carve((size_t)GG * 128 * 4);
    float* bnstat= (float*)carve(512 * 4); // [hop][sum|sq][128]
    size_t zlen  = (size_t)((char*)(bnstat + 512) - (char*)degi);
    int* incl    = (int*)carve((size_t)NN * 4);
    int* bsum    = (int*)carve(64 * 4);
    int* rowstart= (int*)carve((size_t)(NN + 1) * 4);
    int* colx    = (int*)carve((size_t)EE * 4);
    unsigned short* Wt = (unsigned short*)carve((size_t)8 * 16384 * 2);

    hipMemsetAsync(degi, 0, zlen, stream);

    const int nsb = (NN + 1023) / 1024;
    k_deg<<<(EE + 255) / 256, 256, 0, stream>>>(dstE, degi, EE);
    k_scan1<<<nsb, 1024, 0, stream>>>(degi, incl, bsum, NN);
    k_scan3<<<(NN + 255) / 256, 256, 0, stream>>>(incl, degi, bsum, dis, rowstart, NN, EE, nsb);
    k_fillprep<<<FILLB + 512, 256, 0, stream>>>(srcE, dstE, rowstart, fillc, colx,
                                                pre_w1, pre_w2, conv_w, conv_w + 16384,
                                                ffnn_w1, ffnn_w1 + 16384, ffnn_w2, ffnn_w2 + 16384,
                                                Wt, EE);

    const int gB = (NN + 127) / 128;
    const float invN = 1.0f / NN;
    // preprocess FFNN + conv0 (dis-prescaled)
    k_mm<<<gB, 512, 0, stream>>>(x_in, nullptr, Wt + 0 * 16384, pre_b1, Wt + 1 * 16384, pre_b2,
                                 Wt + 2 * 16384, dis, nullptr, nullptr, nullptr, nullptr,
                                 invN, 0, 0, xbf, hbf, nullptr, nullptr, NN);
    // hop 0
    k_agg<<<2048, 256, 0, stream>>>(hbf, rowstart, colx, dis, conv_b,
                                    xbf, zbf, bnstat, bnstat + 128, NN);
    k_mm<<<gB, 512, 0, stream>>>(nullptr, zbf, Wt + 4 * 16384, ffnn_b1, Wt + 6 * 16384, ffnn_b2,
                                 Wt + 3 * 16384, dis, bnstat, bnstat + 128, bn_gamma, bn_beta,
                                 invN, 1, 1, xbf, hbf, nullptr, nullptr, NN);
    // hop 1
    k_agg<<<2048, 256, 0, stream>>>(hbf, rowstart, colx, dis, conv_b + 128,
                                    xbf, zbf, bnstat + 256, bnstat + 384, NN);
    // final FFNN + fused graph-mean-pool
    k_mm<<<gB, 512, 0, stream>>>(nullptr, zbf, Wt + 5 * 16384, ffnn_b1 + 128, Wt + 7 * 16384, ffnn_b2 + 128,
                                 nullptr, nullptr, bnstat + 256, bnstat + 384, bn_gamma + 128, bn_beta + 128,
                                 invN, 1, 1, nullptr, nullptr, batch, pooled, NN);
    // post FFNN
    k_post<<<GG, 128, 0, stream>>>(pooled, batch, post_w1, post_b1, post_w2, post_b2,
                                   (float*)d_out, NN, GG);
}